// Round 1
// 801.521 us; speedup vs baseline: 1.0675x; 1.0675x over previous
//
#include <hip/hip_runtime.h>
#include <hip/hip_bf16.h>
#include <stdint.h>

#define BATCH 8
#define NQ 4096
#define NK 4096
#define DD 512
#define BM 128
#define BN 128
#define BK 64

typedef short bf16x8 __attribute__((ext_vector_type(8)));
typedef float f32x4  __attribute__((ext_vector_type(4)));
typedef unsigned short u16x8 __attribute__((ext_vector_type(8)));

__device__ __forceinline__ unsigned short f2bf_rne(float f) {
    union { float f; uint32_t u; } v; v.f = f;
    uint32_t u = v.u;
    u += 0x7FFFu + ((u >> 16) & 1u);   // round-to-nearest-even
    return (unsigned short)(u >> 16);
}

// One wave per 512-elem row: fp32 sum-of-squares (exact inputs) + bf16 convert.
__global__ __launch_bounds__(256) void prep_kernel(
    const float* __restrict__ keys, const float* __restrict__ queries,
    unsigned short* __restrict__ kb, unsigned short* __restrict__ qb,
    float* __restrict__ ksq, float* __restrict__ qsq)
{
    const int wave = threadIdx.x >> 6;
    const int lane = threadIdx.x & 63;
    const int rid  = blockIdx.x * 4 + wave;        // 0..65535
    const int ROWS = BATCH * NQ;                   // 32768 rows per tensor
    const float* src; unsigned short* db; float* dn; int row;
    if (rid < ROWS) { src = keys;    db = kb; dn = ksq; row = rid; }
    else            { src = queries; db = qb; dn = qsq; row = rid - ROWS; }

    const float* p = src + (size_t)row * DD + lane * 8;
    float4 v0 = ((const float4*)p)[0];
    float4 v1 = ((const float4*)p)[1];
    float s = v0.x*v0.x + v0.y*v0.y + v0.z*v0.z + v0.w*v0.w
            + v1.x*v1.x + v1.y*v1.y + v1.z*v1.z + v1.w*v1.w;
    #pragma unroll
    for (int m = 32; m >= 1; m >>= 1) s += __shfl_xor(s, m);

    u16x8 o;
    o[0] = f2bf_rne(v0.x); o[1] = f2bf_rne(v0.y);
    o[2] = f2bf_rne(v0.z); o[3] = f2bf_rne(v0.w);
    o[4] = f2bf_rne(v1.x); o[5] = f2bf_rne(v1.y);
    o[6] = f2bf_rne(v1.z); o[7] = f2bf_rne(v1.w);
    *(u16x8*)(db + (size_t)row * DD + lane * 8) = o;
    if (lane == 0) dn[row] = s;
}

// 128x128 tile NT-GEMM (both operands row-major, contiguous d) with fused
// distance epilogue. 4 waves, each computes a 64x64 sub-tile as 4x4 MFMA
// 16x16x32_bf16 tiles. Staging: global_load_lds width=16, XOR-swizzled
// granules so ds_read_b128 is ~conflict-free.
// MFMA operand order is SWAPPED (mfma(keys_frag, queries_frag)) so the
// accumulator register index maps to consecutive key columns -> float4
// stores; lane&15 maps to the query row.
__global__ __launch_bounds__(256) void score_kernel(
    const unsigned short* __restrict__ qb, const unsigned short* __restrict__ kb,
    const float* __restrict__ qsq, const float* __restrict__ ksq,
    float* __restrict__ out)
{
    __shared__ unsigned short sA[BM * BK];  // 16 KB
    __shared__ unsigned short sB[BN * BK];  // 16 KB

    const int b    = blockIdx.z;
    const int tm   = blockIdx.y * BM;      // query-row base
    const int tn   = blockIdx.x * BN;      // key-col base
    const int tid  = threadIdx.x;
    const int wave = tid >> 6;
    const int lane = tid & 63;
    const int wm   = wave & 1;
    const int wn   = wave >> 1;

    const unsigned short* Ab = qb + (size_t)b * NQ * DD;
    const unsigned short* Bb = kb + (size_t)b * NK * DD;

    const int r8  = lane >> 3;             // row within 8-row staging group
    const int gsw = (lane & 7) ^ r8;       // swizzled source granule (8 bf16)

    const int frow = lane & 15;            // fragment row index within 16-tile
    const int fq   = lane >> 4;            // quad index 0..3
    const int gx   = frow & 7;             // XOR key for LDS read swizzle

    // Hoisted staging base pointers (advance by BK per k-tile).
    const unsigned short* ga0 = Ab + (size_t)(tm + wave * 32 + r8) * DD + gsw * 8;
    const unsigned short* gb0 = Bb + (size_t)(tn + wave * 32 + r8) * DD + gsw * 8;

    f32x4 acc[4][4] = {};

    for (int kt = 0; kt < DD / BK; ++kt) {
        const int k0 = kt * BK;
        #pragma unroll
        for (int j = 0; j < 4; ++j) {
            const int rloc = wave * 32 + j * 8;   // wave-uniform tile-row base
            __builtin_amdgcn_global_load_lds(
                (const __attribute__((address_space(1))) void*)(ga0 + (size_t)j * 8 * DD + k0),
                (__attribute__((address_space(3))) void*)&sA[rloc * BK],
                16, 0, 0);
            __builtin_amdgcn_global_load_lds(
                (const __attribute__((address_space(1))) void*)(gb0 + (size_t)j * 8 * DD + k0),
                (__attribute__((address_space(3))) void*)&sB[rloc * BK],
                16, 0, 0);
        }
        __syncthreads();

        #pragma unroll
        for (int ks = 0; ks < BK / 32; ++ks) {
            bf16x8 af[4], bf[4];
            const int g_ = (ks * 4 + fq) ^ gx;    // same for A and B (rows ≡ frow mod 8)
            #pragma unroll
            for (int t = 0; t < 4; ++t) {
                const int ra = wm * 64 + t * 16 + frow;
                af[t] = *(const bf16x8*)&sA[ra * BK + g_ * 8];
                const int rb = wn * 64 + t * 16 + frow;
                bf[t] = *(const bf16x8*)&sB[rb * BK + g_ * 8];
            }
            #pragma unroll
            for (int mt = 0; mt < 4; ++mt) {
                #pragma unroll
                for (int nt = 0; nt < 4; ++nt) {
                    // Swapped operands: D[row=key][col=query] = K·Q^T
                    acc[mt][nt] = __builtin_amdgcn_mfma_f32_16x16x32_bf16(
                        bf[nt], af[mt], acc[mt][nt], 0, 0, 0);
                }
            }
        }
        __syncthreads();
    }

    // Epilogue: d2 = qsq + ksq - 2*qk; out = 1/(1+sqrt(max(d2, EPS)))
    // Swapped C/D layout: col(lane&15) = query row, reg+(lane>>4)*4 = key col.
    // => lane holds 4 CONSECUTIVE key columns per (mt,nt): float4 store.
    const float* qn = qsq + b * NQ;
    const float* kn = ksq + b * NK;
    float* ob = out + (size_t)b * NQ * NK;

    const int kcol0 = tn + wn * 64 + fq * 4;     // first of 4 consecutive keys
    float kv[4][4];                              // [nt][r], statically indexed
    #pragma unroll
    for (int nt = 0; nt < 4; ++nt)
        *(f32x4*)kv[nt] = *(const f32x4*)&kn[kcol0 + nt * 16];

    #pragma unroll
    for (int mt = 0; mt < 4; ++mt) {
        const int q = tm + wm * 64 + mt * 16 + frow;
        const float qv = qn[q];
        float* orow = ob + (size_t)q * NK + kcol0;
        #pragma unroll
        for (int nt = 0; nt < 4; ++nt) {
            f32x4 o;
            #pragma unroll
            for (int r = 0; r < 4; ++r) {
                float d2 = (qv + kv[nt][r]) - 2.0f * acc[mt][nt][r];
                d2 = fmaxf(d2, 1e-12f);
                const float dist = __builtin_amdgcn_sqrtf(d2);   // v_sqrt_f32
                o[r] = __builtin_amdgcn_rcpf(1.0f + dist);       // v_rcp_f32
            }
            *(f32x4*)(orow + nt * 16) = o;
        }
    }
}

extern "C" void kernel_launch(void* const* d_in, const int* in_sizes, int n_in,
                              void* d_out, int out_size, void* d_ws, size_t ws_size,
                              hipStream_t stream) {
    (void)in_sizes; (void)n_in; (void)out_size; (void)ws_size;
    const float* keys    = (const float*)d_in[0];   // (8,4096,512)
    const float* queries = (const float*)d_in[1];   // (8,4096,512)
    float* out = (float*)d_out;                     // (8,4096,4096)

    char* ws = (char*)d_ws;
    unsigned short* qb  = (unsigned short*)ws;                              // 32 MB bf16 queries
    unsigned short* kb  = (unsigned short*)(ws + ((size_t)32 << 20));       // 32 MB bf16 keys
    float*          qsq = (float*)(ws + ((size_t)64 << 20));                // 128 KB
    float*          ksq = (float*)(ws + ((size_t)64 << 20) + (128 << 10));  // 128 KB

    prep_kernel<<<dim3((2 * BATCH * NQ) / 4 / 1), 256, 0, stream>>>(
        keys, queries, kb, qb, ksq, qsq);  // 65536 rows / 4 waves = 16384 blocks

    score_kernel<<<dim3(NK / BN, NQ / BM, BATCH), 256, 0, stream>>>(
        qb, kb, qsq, ksq, out);
}

// Round 2
// 767.662 us; speedup vs baseline: 1.1145x; 1.0441x over previous
//
#include <hip/hip_runtime.h>
#include <hip/hip_bf16.h>
#include <stdint.h>

#define BATCH 8
#define NQ 4096
#define NK 4096
#define DD 512
#define BM 256
#define BN 256
#define BK 64
#define NKT (DD / BK)   // 8 k-tiles

typedef short bf16x8 __attribute__((ext_vector_type(8)));
typedef float f32x4  __attribute__((ext_vector_type(4)));
typedef unsigned short u16x8 __attribute__((ext_vector_type(8)));

__device__ __forceinline__ unsigned short f2bf_rne(float f) {
    union { float f; uint32_t u; } v; v.f = f;
    uint32_t u = v.u;
    u += 0x7FFFu + ((u >> 16) & 1u);   // round-to-nearest-even
    return (unsigned short)(u >> 16);
}

// One wave per 512-elem row: fp32 sum-of-squares (exact inputs) + bf16 convert.
__global__ __launch_bounds__(256) void prep_kernel(
    const float* __restrict__ keys, const float* __restrict__ queries,
    unsigned short* __restrict__ kb, unsigned short* __restrict__ qb,
    float* __restrict__ ksq, float* __restrict__ qsq)
{
    const int wave = threadIdx.x >> 6;
    const int lane = threadIdx.x & 63;
    const int rid  = blockIdx.x * 4 + wave;        // 0..65535
    const int ROWS = BATCH * NQ;                   // 32768 rows per tensor
    const float* src; unsigned short* db; float* dn; int row;
    if (rid < ROWS) { src = keys;    db = kb; dn = ksq; row = rid; }
    else            { src = queries; db = qb; dn = qsq; row = rid - ROWS; }

    const float* p = src + (size_t)row * DD + lane * 8;
    float4 v0 = ((const float4*)p)[0];
    float4 v1 = ((const float4*)p)[1];
    float s = v0.x*v0.x + v0.y*v0.y + v0.z*v0.z + v0.w*v0.w
            + v1.x*v1.x + v1.y*v1.y + v1.z*v1.z + v1.w*v1.w;
    #pragma unroll
    for (int m = 32; m >= 1; m >>= 1) s += __shfl_xor(s, m);

    u16x8 o;
    o[0] = f2bf_rne(v0.x); o[1] = f2bf_rne(v0.y);
    o[2] = f2bf_rne(v0.z); o[3] = f2bf_rne(v0.w);
    o[4] = f2bf_rne(v1.x); o[5] = f2bf_rne(v1.y);
    o[6] = f2bf_rne(v1.z); o[7] = f2bf_rne(v1.w);
    *(u16x8*)(db + (size_t)row * DD + lane * 8) = o;
    if (lane == 0) dn[row] = s;
}

// 256x256 tile NT-GEMM, 8 waves (2M x 4N), per-wave 128x64 output as 8x4
// MFMA 16x16x32_bf16 tiles. Double-buffered LDS (128 KiB), 2-phase prefetch:
// issue next k-tile's global_load_lds before computing the current one, so
// L2/L3 load latency hides under the 64-MFMA compute phase. XOR-swizzled
// granules keep ds_read_b128 conflict-free. MFMA operands swapped
// (mfma(keys, queries)) so acc reg index maps to consecutive key columns
// -> float4 stores.
__global__ __launch_bounds__(512, 2) void score_kernel(
    const unsigned short* __restrict__ qb, const unsigned short* __restrict__ kb,
    const float* __restrict__ qsq, const float* __restrict__ ksq,
    float* __restrict__ out)
{
    __shared__ unsigned short sA[2][BM * BK];  // 2 x 32 KB (queries)
    __shared__ unsigned short sB[2][BN * BK];  // 2 x 32 KB (keys)

    const int b    = blockIdx.z;
    const int tm   = blockIdx.y * BM;      // query-row base
    const int tn   = blockIdx.x * BN;      // key-col base
    const int tid  = threadIdx.x;
    const int wave = tid >> 6;             // 0..7
    const int lane = tid & 63;
    const int wm   = wave & 1;             // 2 waves in M -> 128 rows each
    const int wn   = wave >> 1;            // 4 waves in N -> 64 cols each

    const unsigned short* Ab = qb + (size_t)b * NQ * DD;
    const unsigned short* Bb = kb + (size_t)b * NK * DD;

    const int r8  = lane >> 3;             // row within 8-row staging group
    const int gsw = (lane & 7) ^ r8;       // swizzled source granule (8 bf16)

    const int frow = lane & 15;            // fragment row index within 16-tile
    const int fq   = lane >> 4;            // quad index 0..3
    const int gx   = frow & 7;             // XOR key for LDS read swizzle

    // Each wave stages 32 rows of A and 32 rows of B per k-tile.
    const unsigned short* ga0 = Ab + (size_t)(tm + wave * 32 + r8) * DD + gsw * 8;
    const unsigned short* gb0 = Bb + (size_t)(tn + wave * 32 + r8) * DD + gsw * 8;

    f32x4 acc[8][4] = {};

    // ---- prologue: stage k-tile 0 into buffer 0 ----
    #pragma unroll
    for (int j = 0; j < 4; ++j) {
        const int rloc = wave * 32 + j * 8;
        __builtin_amdgcn_global_load_lds(
            (const __attribute__((address_space(1))) void*)(ga0 + (size_t)j * 8 * DD),
            (__attribute__((address_space(3))) void*)&sA[0][rloc * BK], 16, 0, 0);
        __builtin_amdgcn_global_load_lds(
            (const __attribute__((address_space(1))) void*)(gb0 + (size_t)j * 8 * DD),
            (__attribute__((address_space(3))) void*)&sB[0][rloc * BK], 16, 0, 0);
    }
    __syncthreads();   // vmcnt(0) + barrier: buf0 ready

    for (int kt = 0; kt < NKT; ++kt) {
        const int cur = kt & 1;
        // ---- issue next k-tile's staging loads (overlaps with compute) ----
        if (kt + 1 < NKT) {
            const int nxt = cur ^ 1;
            const int k0 = (kt + 1) * BK;
            #pragma unroll
            for (int j = 0; j < 4; ++j) {
                const int rloc = wave * 32 + j * 8;
                __builtin_amdgcn_global_load_lds(
                    (const __attribute__((address_space(1))) void*)(ga0 + (size_t)j * 8 * DD + k0),
                    (__attribute__((address_space(3))) void*)&sA[nxt][rloc * BK], 16, 0, 0);
                __builtin_amdgcn_global_load_lds(
                    (const __attribute__((address_space(1))) void*)(gb0 + (size_t)j * 8 * DD + k0),
                    (__attribute__((address_space(3))) void*)&sB[nxt][rloc * BK], 16, 0, 0);
            }
        }

        // ---- compute current k-tile ----
        #pragma unroll
        for (int ks = 0; ks < BK / 32; ++ks) {
            bf16x8 af[8], bf[4];
            const int g_ = (ks * 4 + fq) ^ gx;   // rows of af/bf are ≡ frow mod 8
            #pragma unroll
            for (int t = 0; t < 8; ++t) {
                const int ra = wm * 128 + t * 16 + frow;
                af[t] = *(const bf16x8*)&sA[cur][ra * BK + g_ * 8];
            }
            #pragma unroll
            for (int t = 0; t < 4; ++t) {
                const int rb = wn * 64 + t * 16 + frow;
                bf[t] = *(const bf16x8*)&sB[cur][rb * BK + g_ * 8];
            }
            __builtin_amdgcn_s_setprio(1);
            #pragma unroll
            for (int mt = 0; mt < 8; ++mt) {
                #pragma unroll
                for (int nt = 0; nt < 4; ++nt) {
                    // Swapped operands: D[row=key][col=query] = K·Q^T
                    acc[mt][nt] = __builtin_amdgcn_mfma_f32_16x16x32_bf16(
                        bf[nt], af[mt], acc[mt][nt], 0, 0, 0);
                }
            }
            __builtin_amdgcn_s_setprio(0);
        }
        // Drains this iteration's staging loads (vmcnt(0)) + barrier:
        // next buffer is ready, and everyone is done reading cur.
        __syncthreads();
    }

    // Epilogue: d2 = qsq + ksq - 2*qk; out = 1/(1+sqrt(max(d2, EPS)))
    // Swapped C/D layout: col(lane&15) = query row, reg+(lane>>4)*4 = key col.
    // => lane holds 4 CONSECUTIVE key columns per (mt,nt): float4 store.
    const float* qn = qsq + b * NQ;
    const float* kn = ksq + b * NK;
    float* ob = out + (size_t)b * NQ * NK;

    const int kcol0 = tn + wn * 64 + fq * 4;     // first of 4 consecutive keys
    float kv[4][4];                              // [nt][r], statically indexed
    #pragma unroll
    for (int nt = 0; nt < 4; ++nt)
        *(f32x4*)kv[nt] = *(const f32x4*)&kn[kcol0 + nt * 16];

    #pragma unroll
    for (int mt = 0; mt < 8; ++mt) {
        const int q = tm + wm * 128 + mt * 16 + frow;
        const float qv = qn[q];
        float* orow = ob + (size_t)q * NK + kcol0;
        #pragma unroll
        for (int nt = 0; nt < 4; ++nt) {
            f32x4 o;
            #pragma unroll
            for (int r = 0; r < 4; ++r) {
                float d2 = (qv + kv[nt][r]) - 2.0f * acc[mt][nt][r];
                d2 = fmaxf(d2, 1e-12f);
                const float dist = __builtin_amdgcn_sqrtf(d2);   // v_sqrt_f32
                o[r] = __builtin_amdgcn_rcpf(1.0f + dist);       // v_rcp_f32
            }
            *(f32x4*)(orow + nt * 16) = o;
        }
    }
}

extern "C" void kernel_launch(void* const* d_in, const int* in_sizes, int n_in,
                              void* d_out, int out_size, void* d_ws, size_t ws_size,
                              hipStream_t stream) {
    (void)in_sizes; (void)n_in; (void)out_size; (void)ws_size;
    const float* keys    = (const float*)d_in[0];   // (8,4096,512)
    const float* queries = (const float*)d_in[1];   // (8,4096,512)
    float* out = (float*)d_out;                     // (8,4096,4096)

    char* ws = (char*)d_ws;
    unsigned short* qb  = (unsigned short*)ws;                              // 32 MB bf16 queries
    unsigned short* kb  = (unsigned short*)(ws + ((size_t)32 << 20));       // 32 MB bf16 keys
    float*          qsq = (float*)(ws + ((size_t)64 << 20));                // 128 KB
    float*          ksq = (float*)(ws + ((size_t)64 << 20) + (128 << 10));  // 128 KB

    prep_kernel<<<dim3((2 * BATCH * NQ) / 4 / 1), 256, 0, stream>>>(
        keys, queries, kb, qb, ksq, qsq);  // 65536 rows / 4 waves = 16384 blocks

    score_kernel<<<dim3(NK / BN, NQ / BM, BATCH), 512, 0, stream>>>(
        qb, kb, qsq, ksq, out);
}